// Round 2
// baseline (143.986 us; speedup 1.0000x reference)
//
#include <hip/hip_runtime.h>
#include <hip/hip_bf16.h>

#define BB 512
#define TT 2048
#define SS 128
#define LL 64
#define PP (TT - LL + 1)   // 1985

// d_ws float-offset layout (total ~1.02 MB, ws is much larger):
//   [0, 262144)        partial max_g per (j, b, s):  part[(j*512+b)*128 + s]
//   [262144, 262272)   ssums[s] = sum(shapelet[s])
//   [262272, 262400)   s2[s]    = sum(shapelet[s]^2)
//   byte 1049600..     bf16 shapelets [S][L] (16 KB), 16B aligned
#define WS_PART 0
#define WS_SSUM 262144
#define WS_S2   262272
#define WS_SHB_BYTE 1049600

typedef __attribute__((ext_vector_type(8))) short  short8;
typedef __attribute__((ext_vector_type(4))) float  float4v;

union U8 { short8 v; unsigned long long u[2]; };

__device__ __forceinline__ unsigned f2bf1(float f) {
  union { float f; unsigned u; } v; v.f = f;
  return (v.u + 0x7FFFu + ((v.u >> 16) & 1u)) >> 16;   // RNE fp32->bf16
}

// ---------------- prep: shapelets -> bf16 + per-shapelet sums ----------------
__global__ __launch_bounds__(256)
void prep_kernel(const float* __restrict__ shg, float* __restrict__ ws) {
  const int t = threadIdx.x;
  const int sidx = t >> 1, l0 = (t & 1) * 32;
  const float* rowp = shg + sidx * LL + l0;
  unsigned* shbw = (unsigned*)((char*)ws + WS_SHB_BYTE);
  float sum = 0.f, sq = 0.f;
  #pragma unroll
  for (int l = 0; l < 32; l += 2) {
    float a = rowp[l], bv = rowp[l + 1];
    sum += a + bv;
    sq = fmaf(a, a, sq);
    sq = fmaf(bv, bv, sq);
    shbw[(sidx * LL + l0 + l) >> 1] = f2bf1(a) | (f2bf1(bv) << 16);
  }
  sum += __shfl_xor(sum, 1);
  sq  += __shfl_xor(sq, 1);
  if ((t & 1) == 0) { ws[WS_SSUM + sidx] = sum; ws[WS_S2 + sidx] = sq; }
}

// ---------------- main: 4 blocks per sample, 512 windows each ----------------
// wave w: s-half = w&1 (64 shapelets), p-half = w>>1 (64 windows per iter), 4 iters.
// d2 = c0[p] + s2[s] + m2[p]*ss[s] - 2*cross  ==  s2[s] - 2*(cross + Cinit)
//   with Cinit = -0.5*(c0[p] + m2[p]*ss[s])  folded into the MFMA C operand.
// We store c0h = -0.5*c0, m2h = -0.5*m2 and track max_g = max(cross + Cinit).
__global__ __launch_bounds__(256, 4)
void shapelet_main(const float* __restrict__ x, float* ws) {
  __shared__ float xf[640];                    // staged x slice (zero-padded)
  __shared__ unsigned long long xcp[4][152];   // 4 element-shifted bf16 copies
  __shared__ float c0h[512], m2h[512];         // -c0/2 (or -INF), -mean
  __shared__ float wminl[256];

  const int t = threadIdx.x;
  const int bid = blockIdx.x;
  const int b = bid >> 2, j = bid & 3;
  const int pgbase = j * 512;

  // ---- stage x slice [pgbase, pgbase+640) with tail zero-pad ----
  if (t < 160) {
    int g0 = pgbase + 4 * t;
    float4v v;
    if (g0 + 3 < TT) {
      v = *(const float4v*)(x + (size_t)b * TT + g0);
    } else {
      #pragma unroll
      for (int k = 0; k < 4; ++k)
        v[k] = (g0 + k < TT) ? x[(size_t)b * TT + g0 + k] : 0.f;
    }
    *(float4v*)(xf + 4 * t) = v;
  }

  // ---- per-lane: B fragments + ssums straight from global (L2 broadcast) ----
  const int lane = t & 63, wave = t >> 6;
  const int n = lane & 15, q = lane >> 4;
  const int shalf = wave & 1, phalf = wave >> 1;

  const short8* shb8 = (const short8*)((const char*)ws + WS_SHB_BYTE);
  short8 bf[2][4];
  float ssl[4];
  #pragma unroll
  for (int st = 0; st < 4; ++st) {
    const int row = shalf * 64 + st * 16 + n;
    #pragma unroll
    for (int kb = 0; kb < 2; ++kb)
      bf[kb][st] = shb8[(row * LL + kb * 32 + q * 8) >> 3];
    ssl[st] = ws[WS_SSUM + row];
  }

  __syncthreads();

  // ---- build 4 shifted bf16 copies of xf ----
  if (t < 152) {
    float4v a = *(const float4v*)(xf + 4 * t);
    float4v bv = *(const float4v*)(xf + 4 * t + 4);
    float e[8] = {a[0], a[1], a[2], a[3], bv[0], bv[1], bv[2], bv[3]};
    #pragma unroll
    for (int c = 0; c < 4; ++c) {
      unsigned long long pk =
          (unsigned long long)f2bf1(e[c]) |
          ((unsigned long long)f2bf1(e[c + 1]) << 16) |
          ((unsigned long long)f2bf1(e[c + 2]) << 32) |
          ((unsigned long long)f2bf1(e[c + 3]) << 48);
      xcp[c][t] = pk;
    }
  }

  // ---- sliding-window stats: 2 windows per thread ----
  {
    const int p0 = 2 * t;                     // 0..510
    const int rot = ((t >> 4) & 3) * 8;       // stagger to reduce bank conflicts
    float s = 0.f, qq = 0.f;
    for (int l = 0; l < 64; ++l) {
      float v = xf[p0 + ((l + rot) & 63)];
      s += v; qq = fmaf(v, v, qq);
    }
    if (pgbase + p0 < PP) {
      c0h[p0] = -0.5f * (qq - s * s * (1.f / 64.f));
      m2h[p0] = s * (-1.f / 64.f);
    } else { c0h[p0] = -INFINITY; m2h[p0] = 0.f; }
    float vo = xf[p0], vi = xf[p0 + 64];
    s += vi - vo;
    qq += fmaf(vi, vi, -vo * vo);
    if (pgbase + p0 + 1 < PP) {
      c0h[p0 + 1] = -0.5f * (qq - s * s * (1.f / 64.f));
      m2h[p0 + 1] = s * (-1.f / 64.f);
    } else { c0h[p0 + 1] = -INFINITY; m2h[p0 + 1] = 0.f; }
  }

  __syncthreads();

  // ---- main MFMA loop ----
  const int c = n & 3;
  const int lw = (n >> 2) + (q << 1);          // per-lane word offset
  const unsigned long long* xc = &xcp[c][0];

  float rmax[4];
  #pragma unroll
  for (int st = 0; st < 4; ++st) rmax[st] = -INFINITY;

  #pragma unroll
  for (int iter = 0; iter < 4; ++iter) {
    const int pbase = iter * 128 + phalf * 64;
    #pragma unroll
    for (int mt = 0; mt < 4; ++mt) {
      const int p0 = pbase + mt * 16;

      // C-operand init: acc[st][r] = -0.5*(c0 + m2*ss) at p = p0 + q*4 + r
      const int pb = p0 + q * 4;
      float4v c0v = *(const float4v*)&c0h[pb];
      float4v m2v = *(const float4v*)&m2h[pb];
      float4v acc[4];
      #pragma unroll
      for (int st = 0; st < 4; ++st) {
        #pragma unroll
        for (int r = 0; r < 4; ++r)
          acc[st][r] = fmaf(m2v[r], ssl[st], c0v[r]);
      }

      #pragma unroll
      for (int kb = 0; kb < 2; ++kb) {
        const int w0 = ((p0 + kb * 32) >> 2) + lw;
        U8 a;
        a.u[0] = xc[w0];
        a.u[1] = xc[w0 + 1];
        #pragma unroll
        for (int st = 0; st < 4; ++st)
          acc[st] = __builtin_amdgcn_mfma_f32_16x16x32_bf16(
              a.v, bf[kb][st], acc[st], 0, 0, 0);
      }

      #pragma unroll
      for (int st = 0; st < 4; ++st) {
        #pragma unroll
        for (int r = 0; r < 4; ++r)
          rmax[st] = fmaxf(rmax[st], acc[st][r]);
      }
    }
  }

  // ---- reduce across q (same s), then across p-half waves via LDS ----
  #pragma unroll
  for (int st = 0; st < 4; ++st) {
    float v = rmax[st];
    v = fmaxf(v, __shfl_xor(v, 16));
    v = fmaxf(v, __shfl_xor(v, 32));
    if (q == 0) wminl[wave * 64 + st * 16 + n] = v;
  }
  __syncthreads();

  if (t < 128) {
    const int sh = t >> 6, k = t & 63;
    float v = fmaxf(wminl[sh * 64 + k], wminl[(sh + 2) * 64 + k]);
    ws[WS_PART + ((size_t)j * 512 + b) * 128 + t] = v;
  }
}

// ---------------- combine: min over j blocks, add s2, sqrt ----------------
__global__ __launch_bounds__(256)
void combine_kernel(const float* __restrict__ ws, float* __restrict__ out) {
  const int tid = blockIdx.x * 256 + threadIdx.x;   // 0 .. 65535
  const int s = tid & 127;
  float g = ws[WS_PART + tid];
  g = fmaxf(g, ws[WS_PART + 65536 + tid]);
  g = fmaxf(g, ws[WS_PART + 131072 + tid]);
  g = fmaxf(g, ws[WS_PART + 196608 + tid]);
  float d2 = fmaf(-2.f, g, ws[WS_S2 + s]);
  out[tid] = sqrtf(fmaxf(d2, 0.f));
}

extern "C" void kernel_launch(void* const* d_in, const int* in_sizes, int n_in,
                              void* d_out, int out_size, void* d_ws, size_t ws_size,
                              hipStream_t stream) {
  const float* x  = (const float*)d_in[0];
  const float* sh = (const float*)d_in[1];
  float* out = (float*)d_out;
  float* ws = (float*)d_ws;
  prep_kernel<<<dim3(1), dim3(256), 0, stream>>>(sh, ws);
  shapelet_main<<<dim3(BB * 4), dim3(256), 0, stream>>>(x, ws);
  combine_kernel<<<dim3(256), dim3(256), 0, stream>>>(ws, out);
}

// Round 3
// 94.426 us; speedup vs baseline: 1.5249x; 1.5249x over previous
//
#include <hip/hip_runtime.h>
#include <hip/hip_bf16.h>

#define BB 512
#define TT 2048
#define SS 128
#define LL 64
#define PP (TT - LL + 1)   // 1985

// ws float-offset layout:
//   [0, 65536)        partial g (j=0):  part[b*128 + s]
//   [65536, 131072)   partial g (j=1)
//   [131072, 131200)  s2c[s] = sum(scent^2) + 64*mean(s)^2
//   byte 1048576..    centered bf16 shapelets, padded rows: 128 x 72 shorts (18432 B)
#define WS_PART 0
#define WS_S2C  131072
#define WS_SHB_BYTE 1048576
#define SH_ROW_SHORTS 72          // 64 data + 8 pad (row stride 144 B)

typedef __attribute__((ext_vector_type(8))) short  short8;
typedef __attribute__((ext_vector_type(4))) float  float4v;

union U8 { short8 v; unsigned long long u[2]; };

__device__ __forceinline__ unsigned f2bf1(float f) {
  union { float f; unsigned u; } v; v.f = f;
  return (v.u + 0x7FFFu + ((v.u >> 16) & 1u)) >> 16;   // RNE fp32->bf16
}

// ---------- prep: center shapelets, bf16-pack (padded rows), s2c ----------
__global__ __launch_bounds__(64)
void prep_kernel(const float* __restrict__ shg, float* __restrict__ ws) {
  const int s = blockIdx.x, l = threadIdx.x;
  float v = shg[s * LL + l];
  float sum = v;
  #pragma unroll
  for (int off = 1; off < 64; off <<= 1) sum += __shfl_xor(sum, off);
  const float mean = sum * (1.f / 64.f);
  const float sc = v - mean;
  float sq = sc * sc;
  #pragma unroll
  for (int off = 1; off < 64; off <<= 1) sq += __shfl_xor(sq, off);

  unsigned bfu = f2bf1(sc);
  unsigned other = __shfl_down(bfu, 1);
  if ((l & 1) == 0) {
    unsigned* shbw = (unsigned*)((char*)ws + WS_SHB_BYTE);
    shbw[s * (SH_ROW_SHORTS / 2) + (l >> 1)] = bfu | (other << 16);
  }
  if (l == 0) ws[WS_S2C + s] = sq + 64.f * mean * mean;
}

// ---------- main: 2 blocks/sample, 1024 windows each, wave = 256 p x 128 s ----------
__global__ __launch_bounds__(256)
void shapelet_main(const float* __restrict__ x, float* ws) {
  __shared__ float xf[1112];                   // fp32 x slice, zero-padded
  __shared__ unsigned long long xcp[4][276];   // 4 element-shifted bf16 copies
  __shared__ short shb[SS * SH_ROW_SHORTS];    // centered bf16 shapelets (padded)
  __shared__ float c0h[1024];                  // -0.5*c0[p], or -INF for invalid p
  __shared__ float wred[4 * 128];

  const int t = threadIdx.x;
  const int bid = blockIdx.x;
  const int b = bid >> 1, j = bid & 1;
  const int pgbase = j * 1024;

  // ---- stage x slice [pgbase, pgbase+1112) with zero-pad ----
  for (int idx = t; idx < 278; idx += 256) {
    const int g0 = pgbase + 4 * idx;
    float4v v;
    if (g0 + 3 < TT) {
      v = *(const float4v*)(x + (size_t)b * TT + g0);
    } else {
      #pragma unroll
      for (int k = 0; k < 4; ++k)
        v[k] = (g0 + k < TT) ? x[(size_t)b * TT + g0 + k] : 0.f;
    }
    *(float4v*)(xf + 4 * idx) = v;
  }

  // ---- stage centered bf16 shapelets (18432 B) global -> LDS ----
  {
    const float4v* src = (const float4v*)((const char*)ws + WS_SHB_BYTE);
    float4v* dst = (float4v*)shb;
    #pragma unroll
    for (int k = 0; k < 5; ++k) {
      const int idx = t + 256 * k;
      if (idx < 1152) dst[idx] = src[idx];
    }
  }

  __syncthreads();

  // ---- build 4 element-shifted bf16 copies of xf ----
  for (int w = t; w < 276; w += 256) {
    float4v a = *(const float4v*)(xf + 4 * w);
    float4v bv = *(const float4v*)(xf + 4 * w + 4);
    float e[8] = {a[0], a[1], a[2], a[3], bv[0], bv[1], bv[2], bv[3]};
    #pragma unroll
    for (int c = 0; c < 4; ++c) {
      unsigned long long pk =
          (unsigned long long)f2bf1(e[c]) |
          ((unsigned long long)f2bf1(e[c + 1]) << 16) |
          ((unsigned long long)f2bf1(e[c + 2]) << 32) |
          ((unsigned long long)f2bf1(e[c + 3]) << 48);
      xcp[c][w] = pk;
    }
  }

  // ---- window stats: thread t -> windows 4t..4t+3, vectorized LDS reads ----
  {
    const float4v* xf4 = (const float4v*)xf;
    float S = 0.f, Q = 0.f;
    float4v v0 = xf4[t];
    {
      float4v v = v0;
      #pragma unroll
      for (int ch = 0; ch < 16; ++ch) {
        S += (v[0] + v[1]) + (v[2] + v[3]);
        Q = fmaf(v[0], v[0], Q); Q = fmaf(v[1], v[1], Q);
        Q = fmaf(v[2], v[2], Q); Q = fmaf(v[3], v[3], Q);
        if (ch < 15) v = xf4[t + ch + 1];
      }
    }
    float4v vN = xf4[t + 16];
    const int p0 = 4 * t;
    #pragma unroll
    for (int r = 0; r < 4; ++r) {
      const bool valid = (pgbase + p0 + r) < PP;
      const float c0 = Q - S * S * (1.f / 64.f);
      c0h[p0 + r] = valid ? (-0.5f * c0) : -INFINITY;
      if (r < 3) {
        const float vin = vN[r], vout = v0[r];
        S += vin - vout;
        Q += fmaf(vin, vin, -vout * vout);
      }
    }
  }

  // ---- per-lane B fragments: all 128 shapelets, from LDS ----
  const int lane = t & 63, wave = t >> 6;
  const int n = lane & 15, q = lane >> 4;

  __syncthreads();

  short8 bf[2][8];
  #pragma unroll
  for (int st = 0; st < 8; ++st) {
    const int row = st * 16 + n;
    #pragma unroll
    for (int kb = 0; kb < 2; ++kb)
      bf[kb][st] = *(const short8*)(shb + row * SH_ROW_SHORTS + kb * 32 + q * 8);
  }

  // ---- main MFMA loop: wave covers p in [wave*256, wave*256+256) ----
  const int c = n & 3;
  const int lw = (n >> 2) + (q << 1);
  const unsigned long long* xc = &xcp[c][0];

  float rmax[8];
  #pragma unroll
  for (int st = 0; st < 8; ++st) rmax[st] = -INFINITY;

  const int pwave = wave * 256;
  #pragma unroll
  for (int mt = 0; mt < 16; ++mt) {
    const int p0 = pwave + mt * 16;

    // C-init: acc = -0.5*c0 at p = p0 + q*4 + r (same for all st)
    const float4v c0v = *(const float4v*)&c0h[p0 + q * 4];

    U8 a0, a1;
    {
      const int w0 = (p0 >> 2) + lw;
      a0.u[0] = xc[w0];      a0.u[1] = xc[w0 + 1];
      a1.u[0] = xc[w0 + 8];  a1.u[1] = xc[w0 + 9];
    }

    float4v acc[8];
    #pragma unroll
    for (int st = 0; st < 8; ++st)
      acc[st] = __builtin_amdgcn_mfma_f32_16x16x32_bf16(a0.v, bf[0][st], c0v, 0, 0, 0);
    #pragma unroll
    for (int st = 0; st < 8; ++st)
      acc[st] = __builtin_amdgcn_mfma_f32_16x16x32_bf16(a1.v, bf[1][st], acc[st], 0, 0, 0);

    #pragma unroll
    for (int st = 0; st < 8; ++st) {
      rmax[st] = fmaxf(rmax[st], fmaxf(fmaxf(acc[st][0], acc[st][1]),
                                       fmaxf(acc[st][2], acc[st][3])));
    }
  }

  // ---- reduce: across q (same s), then across waves ----
  #pragma unroll
  for (int st = 0; st < 8; ++st) {
    float v = rmax[st];
    v = fmaxf(v, __shfl_xor(v, 16));
    v = fmaxf(v, __shfl_xor(v, 32));
    if (q == 0) wred[wave * 128 + st * 16 + n] = v;
  }
  __syncthreads();

  if (t < 128) {
    float v = fmaxf(fmaxf(wred[t], wred[128 + t]),
                    fmaxf(wred[256 + t], wred[384 + t]));
    ws[WS_PART + ((size_t)j * 512 + b) * 128 + t] = v;
  }
}

// ---------- combine: max over j halves, d2 = s2c - 2g, sqrt ----------
__global__ __launch_bounds__(256)
void combine_kernel(const float* __restrict__ ws, float* __restrict__ out) {
  const int tid = blockIdx.x * 256 + threadIdx.x;   // 0 .. 65535
  const int s = tid & 127;
  const float g = fmaxf(ws[WS_PART + tid], ws[WS_PART + 65536 + tid]);
  const float d2 = fmaf(-2.f, g, ws[WS_S2C + s]);
  out[tid] = sqrtf(fmaxf(d2, 0.f));
}

extern "C" void kernel_launch(void* const* d_in, const int* in_sizes, int n_in,
                              void* d_out, int out_size, void* d_ws, size_t ws_size,
                              hipStream_t stream) {
  const float* x  = (const float*)d_in[0];
  const float* sh = (const float*)d_in[1];
  float* out = (float*)d_out;
  float* ws = (float*)d_ws;
  prep_kernel<<<dim3(SS), dim3(64), 0, stream>>>(sh, ws);
  shapelet_main<<<dim3(BB * 2), dim3(256), 0, stream>>>(x, ws);
  combine_kernel<<<dim3(256), dim3(256), 0, stream>>>(ws, out);
}

// Round 4
// 74.793 us; speedup vs baseline: 1.9251x; 1.2625x over previous
//
#include <hip/hip_runtime.h>
#include <hip/hip_bf16.h>

#define BB 512
#define TT 2048
#define SS 128
#define LL 64
#define PP (TT - LL + 1)   // 1985

// ws float-offset layout:
//   [0, 65536)        partial g (j=0):  part[b*128 + s]
//   [65536, 131072)   partial g (j=1)
//   [131072, 131200)  s2c[s] = sum(scent^2) + 64*mean(s)^2
//   byte 1048576..    centered bf16 shapelets, padded rows: 128 x 72 shorts
#define WS_PART 0
#define WS_S2C  131072
#define WS_SHB_BYTE 1048576
#define SH_ROW_SHORTS 72          // 64 data + 8 pad (row stride 144 B)

#define XCP_W 274                 // 8B-words per shifted copy (pad: bank rotate)
#define XF_N  1104                // staged fp32 x elems (covers copy build reads)

typedef __attribute__((ext_vector_type(8))) short  short8;
typedef __attribute__((ext_vector_type(4))) float  float4v;

__device__ __forceinline__ unsigned f2bf1(float f) {
  union { float f; unsigned u; } v; v.f = f;
  return (v.u + 0x7FFFu + ((v.u >> 16) & 1u)) >> 16;   // RNE fp32->bf16
}

// ---------- prep: center shapelets, bf16-pack (padded rows), s2c ----------
__global__ __launch_bounds__(64)
void prep_kernel(const float* __restrict__ shg, float* __restrict__ ws) {
  const int s = blockIdx.x, l = threadIdx.x;
  float v = shg[s * LL + l];
  float sum = v;
  #pragma unroll
  for (int off = 1; off < 64; off <<= 1) sum += __shfl_xor(sum, off);
  const float mean = sum * (1.f / 64.f);
  const float sc = v - mean;
  float sq = sc * sc;
  #pragma unroll
  for (int off = 1; off < 64; off <<= 1) sq += __shfl_xor(sq, off);

  unsigned bfu = f2bf1(sc);
  unsigned other = __shfl_down(bfu, 1);
  if ((l & 1) == 0) {
    unsigned* shbw = (unsigned*)((char*)ws + WS_SHB_BYTE);
    shbw[s * (SH_ROW_SHORTS / 2) + (l >> 1)] = bfu | (other << 16);
  }
  if (l == 0) ws[WS_S2C + s] = sq + 64.f * mean * mean;
}

// ---------- main: 2 blocks/sample, 1024 windows each ----------
// 4 waves: wave w -> shalf = w&1 (64 shapelets), phalf = w>>1 (512 windows).
// d2 = c0[p] + s2c[s] - 2*cross(x, centered_shapelet); C-init = -c0/2,
// track g = max(cross - c0/2); combine: d2 = s2c - 2g.
__global__ __launch_bounds__(256)
void shapelet_main(const float* __restrict__ x, float* ws) {
  __shared__ __align__(16) float xf[XF_N];
  __shared__ __align__(16) unsigned long long xcp[8][XCP_W];
  __shared__ float c0h[1024];
  __shared__ float wred[4 * 64];

  const int t = threadIdx.x;
  const int bid = blockIdx.x;
  const int b = bid >> 1, j = bid & 1;
  const int pgbase = j * 1024;

  const int lane = t & 63, wave = t >> 6;
  const int n = lane & 15, q = lane >> 4;
  const int shalf = wave & 1, phalf = wave >> 1;

  // ---- B fragments straight from global (L2-resident, written by prep) ----
  short8 bf[2][4];
  {
    const short* shb = (const short*)((const char*)ws + WS_SHB_BYTE);
    #pragma unroll
    for (int st = 0; st < 4; ++st) {
      const int row = shalf * 64 + st * 16 + n;
      #pragma unroll
      for (int kb = 0; kb < 2; ++kb)
        bf[kb][st] = *(const short8*)(shb + row * SH_ROW_SHORTS + kb * 32 + q * 8);
    }
  }

  // ---- stage x slice [pgbase, pgbase + XF_N) with zero-pad ----
  for (int idx = t; idx < XF_N / 4; idx += 256) {
    const int g0 = pgbase + 4 * idx;
    float4v v;
    if (g0 + 3 < TT) {
      v = *(const float4v*)(x + (size_t)b * TT + g0);
    } else {
      #pragma unroll
      for (int k = 0; k < 4; ++k)
        v[k] = (g0 + k < TT) ? x[(size_t)b * TT + g0 + k] : 0.f;
    }
    *(float4v*)(xf + 4 * idx) = v;
  }

  __syncthreads();

  // ---- build 8 element-shifted bf16 copies: copy c word w = bf16(xf[4w+c..+3]) ----
  for (int w = t; w < XCP_W; w += 256) {
    float e[11];
    #pragma unroll
    for (int k = 0; k < 11; ++k) e[k] = xf[4 * w + k];
    unsigned bfx[11];
    #pragma unroll
    for (int k = 0; k < 11; ++k) bfx[k] = f2bf1(e[k]);
    #pragma unroll
    for (int c = 0; c < 8; ++c) {
      unsigned long long pk =
          (unsigned long long)bfx[c] |
          ((unsigned long long)bfx[c + 1] << 16) |
          ((unsigned long long)bfx[c + 2] << 32) |
          ((unsigned long long)bfx[c + 3] << 48);
      xcp[c][w] = pk;
    }
  }

  // ---- window stats: thread t -> windows 4t..4t+3 ----
  {
    const float4v* xf4 = (const float4v*)xf;
    float S = 0.f, Q = 0.f;
    float4v v0 = xf4[t];
    {
      float4v v = v0;
      #pragma unroll
      for (int ch = 0; ch < 16; ++ch) {
        S += (v[0] + v[1]) + (v[2] + v[3]);
        Q = fmaf(v[0], v[0], Q); Q = fmaf(v[1], v[1], Q);
        Q = fmaf(v[2], v[2], Q); Q = fmaf(v[3], v[3], Q);
        if (ch < 15) v = xf4[t + ch + 1];
      }
    }
    float4v vN = xf4[t + 16];
    const int p0s = 4 * t;
    #pragma unroll
    for (int r = 0; r < 4; ++r) {
      const bool valid = (pgbase + p0s + r) < PP;
      const float c0 = Q - S * S * (1.f / 64.f);
      c0h[p0s + r] = valid ? (-0.5f * c0) : -INFINITY;
      if (r < 3) {
        const float vin = vN[r], vout = v0[r];
        S += vin - vout;
        Q += fmaf(vin, vin, -vout * vout);
      }
    }
  }

  __syncthreads();

  // ---- main MFMA loop: wave covers p in [phalf*512, phalf*512+512) ----
  const int c = n & 7;
  const int lw = 2 * q + 2 * (n >> 3);         // even => 16B-aligned b128
  const unsigned long long* xc = &xcp[c][0];

  float4v rmax[4];
  #pragma unroll
  for (int st = 0; st < 4; ++st) rmax[st] = { -INFINITY, -INFINITY, -INFINITY, -INFINITY };

  const int pwave = phalf * 512;
  #pragma unroll 2
  for (int mt = 0; mt < 32; ++mt) {
    const int p0 = pwave + mt * 16;
    const int w0 = (p0 >> 2) + lw;

    const short8 a0 = *(const short8*)&xc[w0];
    const short8 a1 = *(const short8*)&xc[w0 + 8];
    const float4v c0v = *(const float4v*)&c0h[p0 + q * 4];

    float4v acc[4];
    #pragma unroll
    for (int st = 0; st < 4; ++st)
      acc[st] = __builtin_amdgcn_mfma_f32_16x16x32_bf16(a0, bf[0][st], c0v, 0, 0, 0);
    #pragma unroll
    for (int st = 0; st < 4; ++st)
      acc[st] = __builtin_amdgcn_mfma_f32_16x16x32_bf16(a1, bf[1][st], acc[st], 0, 0, 0);

    #pragma unroll
    for (int st = 0; st < 4; ++st) {
      #pragma unroll
      for (int r = 0; r < 4; ++r)
        rmax[st][r] = fmaxf(rmax[st][r], acc[st][r]);
    }
  }

  // ---- reduce: 4-vec -> scalar, across q (shfl), across phalf waves (LDS) ----
  #pragma unroll
  for (int st = 0; st < 4; ++st) {
    float v = fmaxf(fmaxf(rmax[st][0], rmax[st][1]),
                    fmaxf(rmax[st][2], rmax[st][3]));
    v = fmaxf(v, __shfl_xor(v, 16));
    v = fmaxf(v, __shfl_xor(v, 32));
    if (q == 0) wred[wave * 64 + st * 16 + n] = v;
  }
  __syncthreads();

  if (t < 128) {
    const int sh = t >> 6, k = t & 63;
    const float v = fmaxf(wred[sh * 64 + k], wred[(sh + 2) * 64 + k]);
    ws[WS_PART + ((size_t)j * 512 + b) * 128 + t] = v;
  }
}

// ---------- combine: max over j halves, d2 = s2c - 2g, sqrt ----------
__global__ __launch_bounds__(256)
void combine_kernel(const float* __restrict__ ws, float* __restrict__ out) {
  const int tid = blockIdx.x * 256 + threadIdx.x;   // 0 .. 65535
  const int s = tid & 127;
  const float g = fmaxf(ws[WS_PART + tid], ws[WS_PART + 65536 + tid]);
  const float d2 = fmaf(-2.f, g, ws[WS_S2C + s]);
  out[tid] = sqrtf(fmaxf(d2, 0.f));
}

extern "C" void kernel_launch(void* const* d_in, const int* in_sizes, int n_in,
                              void* d_out, int out_size, void* d_ws, size_t ws_size,
                              hipStream_t stream) {
  const float* x  = (const float*)d_in[0];
  const float* sh = (const float*)d_in[1];
  float* out = (float*)d_out;
  float* ws = (float*)d_ws;
  prep_kernel<<<dim3(SS), dim3(64), 0, stream>>>(sh, ws);
  shapelet_main<<<dim3(BB * 2), dim3(256), 0, stream>>>(x, ws);
  combine_kernel<<<dim3(256), dim3(256), 0, stream>>>(ws, out);
}

// Round 5
// 71.220 us; speedup vs baseline: 2.0217x; 1.0502x over previous
//
#include <hip/hip_runtime.h>
#include <hip/hip_bf16.h>

#define BB 512
#define TT 2048
#define SS 128
#define LL 64
#define PP (TT - LL + 1)   // 1985

// ws float-offset layout:
//   [131072, 131200)  s2c[s] = sum(scent^2) + 64*mean(s)^2
//   byte 1048576..    centered bf16 shapelets, padded rows: 128 x 72 shorts
#define WS_S2C  131072
#define WS_SHB_BYTE 1048576
#define SH_ROW_SHORTS 72          // 64 data + 8 pad (row stride 144 B)

#define XF_N  2128                // staged fp32 x elems (zero-padded past 2048)
#define XCP_W 530                 // 8B words per shifted copy; (2*530)%32==4 -> copies
                                  // start 4 banks apart => A-reads tile all 32 banks

typedef __attribute__((ext_vector_type(8))) short  short8;
typedef __attribute__((ext_vector_type(4))) float  float4v;

__device__ __forceinline__ unsigned f2bf1(float f) {
  union { float f; unsigned u; } v; v.f = f;
  return (v.u + 0x7FFFu + ((v.u >> 16) & 1u)) >> 16;   // RNE fp32->bf16
}

// ---------- prep: center shapelets, bf16-pack (padded rows), s2c ----------
__global__ __launch_bounds__(64)
void prep_kernel(const float* __restrict__ shg, float* __restrict__ ws) {
  const int s = blockIdx.x, l = threadIdx.x;
  float v = shg[s * LL + l];
  float sum = v;
  #pragma unroll
  for (int off = 1; off < 64; off <<= 1) sum += __shfl_xor(sum, off);
  const float mean = sum * (1.f / 64.f);
  const float sc = v - mean;
  float sq = sc * sc;
  #pragma unroll
  for (int off = 1; off < 64; off <<= 1) sq += __shfl_xor(sq, off);

  unsigned bfu = f2bf1(sc);
  unsigned other = __shfl_down(bfu, 1);
  if ((l & 1) == 0) {
    unsigned* shbw = (unsigned*)((char*)ws + WS_SHB_BYTE);
    shbw[s * (SH_ROW_SHORTS / 2) + (l >> 1)] = bfu | (other << 16);
  }
  if (l == 0) ws[WS_S2C + s] = sq + 64.f * mean * mean;
}

// ---------- main: 1 block (512 thr, 8 waves) per sample ----------
// wave w: shalf = w&1 (64 shapelets), pq = w>>1 (512 windows).
// d2 = c0[p] + s2c[s] - 2*cross(x, centered_shapelet); C-init = -c0/2;
// track g = max(cross - c0/2); out = sqrt(s2c - 2g).
__global__ __launch_bounds__(512)
void shapelet_main(const float* __restrict__ x, const float* __restrict__ ws,
                   float* __restrict__ out) {
  __shared__ __align__(16) float xf[XF_N];
  __shared__ __align__(16) unsigned long long xcp[8][XCP_W];
  __shared__ float c0h[2048];
  __shared__ float wred[8 * 64];

  const int t = threadIdx.x;
  const int b = blockIdx.x;

  const int lane = t & 63, wave = t >> 6;
  const int n = lane & 15, q = lane >> 4;
  const int shalf = wave & 1, pq = wave >> 1;

  // ---- stage x[b] (8 KB) with zero-pad to XF_N ----
  for (int idx = t; idx < XF_N / 4; idx += 512) {
    const int g0 = 4 * idx;
    float4v v = {0.f, 0.f, 0.f, 0.f};
    if (g0 < TT) v = *(const float4v*)(x + (size_t)b * TT + g0);
    *(float4v*)(xf + 4 * idx) = v;
  }

  __syncthreads();

  // ---- build 8 element-shifted bf16 copies (vectorized conflict-free reads) ----
  for (int w = t; w < XCP_W; w += 512) {
    const float4v* xf4 = (const float4v*)xf;
    float4v A = xf4[w], Bv = xf4[w + 1], Cv = xf4[w + 2];
    unsigned bfx[11];
    #pragma unroll
    for (int k = 0; k < 4; ++k) bfx[k] = f2bf1(A[k]);
    #pragma unroll
    for (int k = 0; k < 4; ++k) bfx[4 + k] = f2bf1(Bv[k]);
    #pragma unroll
    for (int k = 0; k < 3; ++k) bfx[8 + k] = f2bf1(Cv[k]);
    #pragma unroll
    for (int c = 0; c < 8; ++c) {
      unsigned long long pk =
          (unsigned long long)bfx[c] |
          ((unsigned long long)bfx[c + 1] << 16) |
          ((unsigned long long)bfx[c + 2] << 32) |
          ((unsigned long long)bfx[c + 3] << 48);
      xcp[c][w] = pk;
    }
  }

  // ---- B fragments from global (L2-resident; latency hides under stats) ----
  short8 bf[2][4];
  {
    const short* shb = (const short*)((const char*)ws + WS_SHB_BYTE);
    #pragma unroll
    for (int st = 0; st < 4; ++st) {
      const int row = shalf * 64 + st * 16 + n;
      #pragma unroll
      for (int kb = 0; kb < 2; ++kb)
        bf[kb][st] = *(const short8*)(shb + row * SH_ROW_SHORTS + kb * 32 + q * 8);
    }
  }

  // ---- window stats: thread t -> windows 4t..4t+3 ----
  {
    const float4v* xf4 = (const float4v*)xf;
    float S = 0.f, Q = 0.f;
    float4v v0 = xf4[t];
    {
      float4v v = v0;
      #pragma unroll
      for (int ch = 0; ch < 16; ++ch) {
        S += (v[0] + v[1]) + (v[2] + v[3]);
        Q = fmaf(v[0], v[0], Q); Q = fmaf(v[1], v[1], Q);
        Q = fmaf(v[2], v[2], Q); Q = fmaf(v[3], v[3], Q);
        if (ch < 15) v = xf4[t + ch + 1];
      }
    }
    float4v vN = xf4[t + 16];
    const int p0s = 4 * t;
    #pragma unroll
    for (int r = 0; r < 4; ++r) {
      const bool valid = (p0s + r) < PP;
      const float c0 = Q - S * S * (1.f / 64.f);
      c0h[p0s + r] = valid ? (-0.5f * c0) : -INFINITY;
      if (r < 3) {
        const float vin = vN[r], vout = v0[r];
        S += vin - vout;
        Q += fmaf(vin, vin, -vout * vout);
      }
    }
  }

  __syncthreads();

  // ---- main MFMA loop: wave covers p in [pq*512, pq*512+512) ----
  const int c = n & 7;
  const int lw = 2 * q + 2 * (n >> 3);         // even => 16B-aligned ds_read_b128
  const unsigned long long* xc = &xcp[c][0];

  float rmax[4];
  #pragma unroll
  for (int st = 0; st < 4; ++st) rmax[st] = -INFINITY;

  const int pwave = pq * 512;
  for (int mt = 0; mt < 32; ++mt) {
    const int p0 = pwave + mt * 16;
    const int w0 = (p0 >> 2) + lw;

    const short8 a0 = *(const short8*)&xc[w0];
    const short8 a1 = *(const short8*)&xc[w0 + 8];
    const float4v c0v = *(const float4v*)&c0h[p0 + q * 4];

    float4v acc[4];
    #pragma unroll
    for (int st = 0; st < 4; ++st)
      acc[st] = __builtin_amdgcn_mfma_f32_16x16x32_bf16(a0, bf[0][st], c0v, 0, 0, 0);
    #pragma unroll
    for (int st = 0; st < 4; ++st)
      acc[st] = __builtin_amdgcn_mfma_f32_16x16x32_bf16(a1, bf[1][st], acc[st], 0, 0, 0);

    #pragma unroll
    for (int st = 0; st < 4; ++st) {
      const float m01 = fmaxf(acc[st][0], acc[st][1]);
      const float m23 = fmaxf(acc[st][2], acc[st][3]);
      rmax[st] = fmaxf(rmax[st], fmaxf(m01, m23));   // -> v_max3 pair
    }
  }

  // ---- reduce: across q (shfl), then across the 4 p-quarter waves (LDS) ----
  #pragma unroll
  for (int st = 0; st < 4; ++st) {
    float v = rmax[st];
    v = fmaxf(v, __shfl_xor(v, 16));
    v = fmaxf(v, __shfl_xor(v, 32));
    if (q == 0) wred[wave * 64 + st * 16 + n] = v;
  }
  __syncthreads();

  if (t < SS) {
    const int g = t >> 6, k = t & 63;            // g = s-half, k = s within half
    float v = fmaxf(fmaxf(wred[(g)*64 + k],       wred[(2 + g) * 64 + k]),
                    fmaxf(wred[(4 + g) * 64 + k], wred[(6 + g) * 64 + k]));
    const float d2 = fmaf(-2.f, v, ws[WS_S2C + t]);
    out[(size_t)b * SS + t] = sqrtf(fmaxf(d2, 0.f));
  }
}

extern "C" void kernel_launch(void* const* d_in, const int* in_sizes, int n_in,
                              void* d_out, int out_size, void* d_ws, size_t ws_size,
                              hipStream_t stream) {
  const float* x  = (const float*)d_in[0];
  const float* sh = (const float*)d_in[1];
  float* out = (float*)d_out;
  float* ws = (float*)d_ws;
  prep_kernel<<<dim3(SS), dim3(64), 0, stream>>>(sh, ws);
  shapelet_main<<<dim3(BB), dim3(512), 0, stream>>>(x, ws, out);
}